// Round 1
// baseline (841.249 us; speedup 1.0000x reference)
//
#include <hip/hip_runtime.h>
#include <cstdint>

#define KTOT 2048   // C*D = 64*32
#define G    8      // batches per block

typedef const __attribute__((address_space(1))) uint32_t gu32;
typedef __attribute__((address_space(3))) uint32_t lu32;

// Transpose W[j][k][m] -> WT[e][k], e = j*32+m.  (256 KB, one-time per launch)
__global__ __launch_bounds__(1024) void wtrans_kernel(const float* __restrict__ W,
                                                      float* __restrict__ WT) {
    int j = blockIdx.x;          // [0,64)
    int t = threadIdx.x;         // [0,1024) = k*32+m
    int k = t >> 5, m = t & 31;
    float v = W[j * 1024 + t];
    WT[(j * 32 + m) * 32 + k] = v;
}

// Fused: S[b,k] = sum_e WT[e][k]*x[b][e];  out[b,i] = tanh(sum_d x[b][i*32+d]*S[b,d])
__global__ __launch_bounds__(256, 2) void ipf_kernel(const float* __restrict__ x,
                                                     const float* __restrict__ WT,
                                                     float* __restrict__ out) {
    extern __shared__ float smemf[];
    float* xlin = smemf;              // [G*KTOT] linear, 64 KB
    float* Slds = smemf + G * KTOT;   // [G*32]
    const int t = threadIdx.x;
    const long long b0 = (long long)blockIdx.x * G;

    // zero S accumulators (t in [0,256) covers G*32 = 256 exactly)
    Slds[t] = 0.0f;

    // ---- stage x -> LDS, 64 KB, global_load_lds width 16 (linear dest) ----
    {
        const int wave = t >> 6;
        const int lane = t & 63;
        const char* gsrc = (const char*)(x + b0 * KTOT);
        #pragma unroll
        for (int it = 0; it < 16; ++it) {
            int off = (wave * 16 + it) * 1024;  // bytes; wave-uniform LDS dest
            __builtin_amdgcn_global_load_lds((gu32*)(gsrc + off + lane * 16),
                                             (lu32*)((char*)smemf + off),
                                             16, 0, 0);
        }
    }
    __syncthreads();

    // ---- phase 1: register-tiled S-GEMM (8b x 8k x 4e per thread-iter) ----
    const int kpos = t & 3;   // k octet: k = kpos*8 + kk
    const int egl  = t >> 2;  // [0,64) e-groups
    float acc[G][8];
    #pragma unroll
    for (int b = 0; b < G; ++b) {
        #pragma unroll
        for (int kk = 0; kk < 8; ++kk) acc[b][kk] = 0.0f;
    }

    const float* wb = WT + kpos * 8;
    #pragma unroll 2
    for (int iter = 0; iter < 8; ++iter) {
        const int e4 = iter * 64 + egl;   // [0,512)
        const int e  = e4 * 4;
        float4 xv[G];
        #pragma unroll
        for (int b = 0; b < G; ++b)
            xv[b] = *(const float4*)(xlin + b * KTOT + e);
        float4 wv[8];
        #pragma unroll
        for (int j = 0; j < 4; ++j) {
            wv[2 * j]     = *(const float4*)(wb + (e + j) * 32);
            wv[2 * j + 1] = *(const float4*)(wb + (e + j) * 32 + 4);
        }
        #pragma unroll
        for (int j = 0; j < 4; ++j) {
            #pragma unroll
            for (int b = 0; b < G; ++b) {
                const float xb = ((const float*)&xv[b])[j];
                acc[b][0] += xb * wv[2 * j].x;
                acc[b][1] += xb * wv[2 * j].y;
                acc[b][2] += xb * wv[2 * j].z;
                acc[b][3] += xb * wv[2 * j].w;
                acc[b][4] += xb * wv[2 * j + 1].x;
                acc[b][5] += xb * wv[2 * j + 1].y;
                acc[b][6] += xb * wv[2 * j + 1].z;
                acc[b][7] += xb * wv[2 * j + 1].w;
            }
        }
    }

    // ---- reduce 64 e-group partials into Slds via LDS fp32 atomics ----
    #pragma unroll
    for (int b = 0; b < G; ++b) {
        #pragma unroll
        for (int kk = 0; kk < 8; ++kk)
            atomicAdd(&Slds[b * 32 + kpos * 8 + kk], acc[b][kk]);
    }
    __syncthreads();

    // ---- phase 2: out[b,i] = tanh(dot(x[b][i*32..], S[b])) ----
    const int i    = t & 63;   // channel
    const int brow = t >> 6;   // 0..3
    #pragma unroll
    for (int rep = 0; rep < 2; ++rep) {
        const int b = brow + rep * 4;
        float s = 0.0f;
        #pragma unroll
        for (int dd = 0; dd < 32; ++dd) {
            const int d = (dd + i) & 31;  // per-lane rotation: bank = (dd+i)&31, conflict-free
            s += xlin[b * KTOT + i * 32 + d] * Slds[b * 32 + d];
        }
        out[(b0 + b) * 64 + i] = tanhf(s);
    }
}

extern "C" void kernel_launch(void* const* d_in, const int* in_sizes, int n_in,
                              void* d_out, int out_size, void* d_ws, size_t ws_size,
                              hipStream_t stream) {
    const float* x  = (const float*)d_in[0];   // [65536,64,32] fp32
    const float* W  = (const float*)d_in[1];   // [64,32,32] fp32
    float* out = (float*)d_out;                // [65536,64] fp32
    float* WT  = (float*)d_ws;                 // 2048*32 fp32 = 256 KB scratch

    const size_t smem_bytes = (size_t)(G * KTOT + G * 32) * sizeof(float); // 66560
    hipFuncSetAttribute((const void*)ipf_kernel,
                        hipFuncAttributeMaxDynamicSharedMemorySize,
                        (int)smem_bytes);

    wtrans_kernel<<<64, 1024, 0, stream>>>(W, WT);
    ipf_kernel<<<65536 / G, 256, smem_bytes, stream>>>(x, WT, out);
}

// Round 2
// 311.233 us; speedup vs baseline: 2.7030x; 2.7030x over previous
//
#include <hip/hip_runtime.h>
#include <cstdint>

#define G   8      // batches per block
#define KT  2048   // C*D = 64*32

typedef const __attribute__((address_space(1))) uint32_t gu32;
typedef __attribute__((address_space(3))) uint32_t lu32;

// W4 layout: W4[e4][k][dd] (e = e4*4+dd, k in [0,32)):  W4[e4*128 + k*4 + dd] = W[j][k][m], e = j*32+m
__global__ __launch_bounds__(1024) void wtrans_kernel(const float* __restrict__ W,
                                                      float* __restrict__ W4) {
    int j = blockIdx.x;           // [0,64)
    int t = threadIdx.x;          // k*32 + m
    int k = t >> 5, m = t & 31;
    int e = j * 32 + m;
    W4[(e >> 2) * 128 + k * 4 + (e & 3)] = W[j * 1024 + t];
}

template <int CTRL>
__device__ __forceinline__ float dpp_shr_add(float v) {
    int moved = __builtin_amdgcn_update_dpp(0, __float_as_int(v), CTRL, 0xF, 0xF, true);
    return v + __int_as_float(moved);
}

// LDS float layout: xs[16384] (swizzled) | P[4*8*65 = 2080] | S[256]
__global__ __launch_bounds__(256, 2) void ipf_kernel(const float* __restrict__ x,
                                                     const float* __restrict__ W4,
                                                     float* __restrict__ out) {
    extern __shared__ float smem[];
    float* xs = smem;                 // 16384 floats, XOR-swizzled at float4 granularity
    float* Pp = smem + G * KT;        // 2080 floats, stride-65 rows
    float* Sl = Pp + 4 * 8 * 65;      // 256 floats

    const int t = threadIdx.x;
    const int w = t >> 6;             // wave id = k-span owner
    const int l = t & 63;             // lane
    const long long b0 = (long long)blockIdx.x * G;

    // ---- stage x -> LDS (64 KB), linear LDS dest, XOR-pre-swizzled global source ----
    {
        const char* gbase = (const char*)(x + b0 * KT);
        const int lbyte = (l * 16) ^ (((l >> 3) & 7) << 4);   // per-lane swizzled source offset
        #pragma unroll
        for (int it = 0; it < 16; ++it) {
            const int chunk = (w * 16 + it) * 1024;           // bytes; multiple of 8KB pattern-safe
            __builtin_amdgcn_global_load_lds((gu32*)(gbase + chunk + lbyte),
                                             (lu32*)((char*)xs + chunk), 16, 0, 0);
        }
    }
    __syncthreads();

    // ---- phase 1: acc[bb][kk] = sum_e x[bb][e] * W4[e][w*8+kk] ----
    float acc[G][8];
    #pragma unroll
    for (int bb = 0; bb < G; ++bb)
        #pragma unroll
        for (int kk = 0; kk < 8; ++kk) acc[bb][kk] = 0.0f;

    const int lsw = l ^ ((l >> 3) & 7);          // swizzled quad index for this lane
    const float4* xs4 = (const float4*)xs;

    #pragma unroll 2
    for (int j = 0; j < 8; ++j) {
        const int e4 = j * 64 + l;               // logical e4 this lane covers
        float4 wv[8];
        const float4* wp = (const float4*)(W4 + e4 * 128 + w * 32);
        #pragma unroll
        for (int q = 0; q < 8; ++q) wv[q] = wp[q];   // 8k x 4dd, contiguous 128B per lane

        const int s4 = j * 64 + lsw;             // swizzled LDS quad
        #pragma unroll
        for (int bb = 0; bb < G; ++bb) {
            const float4 xv = xs4[bb * 512 + s4];
            #pragma unroll
            for (int kk = 0; kk < 8; ++kk) {
                acc[bb][kk] += xv.x * wv[kk].x;
                acc[bb][kk] += xv.y * wv[kk].y;
                acc[bb][kk] += xv.z * wv[kk].z;
                acc[bb][kk] += xv.w * wv[kk].w;
            }
        }
    }

    // ---- intra-wave reduce over 8-lane groups via DPP (VALU pipe, no LDS atomics) ----
    #pragma unroll
    for (int bb = 0; bb < G; ++bb)
        #pragma unroll
        for (int kk = 0; kk < 8; ++kk) {
            float v = acc[bb][kk];
            v = dpp_shr_add<0x111>(v);   // row_shr:1
            v = dpp_shr_add<0x112>(v);   // row_shr:2
            v = dpp_shr_add<0x114>(v);   // row_shr:4 -> lanes with (l&7)==7 hold 8-lane sums
            acc[bb][kk] = v;
        }

    // group leaders write partials: P[(w*8+g)][bb*8+kk], row stride 65 (bank-spread)
    if ((l & 7) == 7) {
        const int g = l >> 3;
        const int rowb = (w * 8 + g) * 65;
        #pragma unroll
        for (int bb = 0; bb < G; ++bb)
            #pragma unroll
            for (int kk = 0; kk < 8; ++kk)
                Pp[rowb + bb * 8 + kk] = acc[bb][kk];
    }
    __syncthreads();

    // ---- gather: S[b][k] = sum_g P[(w(k)*8+g)][b*8+kk]  (256 threads = 8b x 32k) ----
    {
        const int b = t >> 5, k = t & 31;
        const int wq = k >> 3, kk = k & 7;
        float s = 0.0f;
        #pragma unroll
        for (int g = 0; g < 8; ++g)
            s += Pp[(wq * 8 + g) * 65 + b * 8 + kk];
        Sl[t] = s;                                // Sl[b*32+k]
    }
    __syncthreads();

    // ---- phase 2: out[b,i] = tanh(sum_d x[b][i*32+d] * S[b][d]) ----
    const int i = l;                              // channel = lane (coalesced stores)
    #pragma unroll
    for (int rep = 0; rep < 2; ++rep) {
        const int bb = w + rep * 4;
        float s = 0.0f;
        #pragma unroll
        for (int j4 = 0; j4 < 8; ++j4) {
            const int q = j4 ^ (i & 7);           // swizzled access -> conflict-free b128
            const float4 xv = xs4[bb * 512 + i * 8 + q];   // = x[bb][i*32 + j4*4 .. +4]
            const float4 sv = *(const float4*)(Sl + bb * 32 + j4 * 4);  // broadcast
            s += xv.x * sv.x + xv.y * sv.y + xv.z * sv.z + xv.w * sv.w;
        }
        const float e2 = __expf(2.0f * s);        // tanh(s) = 1 - 2/(e^{2s}+1); saturates correctly
        out[(b0 + bb) * 64 + i] = 1.0f - 2.0f / (e2 + 1.0f);
    }
}

extern "C" void kernel_launch(void* const* d_in, const int* in_sizes, int n_in,
                              void* d_out, int out_size, void* d_ws, size_t ws_size,
                              hipStream_t stream) {
    const float* x = (const float*)d_in[0];   // [65536,64,32] fp32
    const float* W = (const float*)d_in[1];   // [64,32,32] fp32
    float* out = (float*)d_out;               // [65536,64] fp32
    float* W4  = (float*)d_ws;                // 512*128 floats = 256 KB scratch

    const size_t smem_bytes = (size_t)(G * KT + 4 * 8 * 65 + 256) * sizeof(float); // 74880 B
    hipFuncSetAttribute((const void*)ipf_kernel,
                        hipFuncAttributeMaxDynamicSharedMemorySize, (int)smem_bytes);

    wtrans_kernel<<<64, 1024, 0, stream>>>(W, W4);
    ipf_kernel<<<65536 / G, 256, smem_bytes, stream>>>(x, W4, out);
}